// Round 1
// baseline (151.002 us; speedup 1.0000x reference)
//
#include <hip/hip_runtime.h>
#include <math.h>

#define C_CLS  64
#define K_SHOTS 512
#define D_DIM  2048
#define BPC    16                         // blocks per class
#define ROWS_PER_BLOCK (K_SHOTS / BPC)    // 32
#define NWAVES 4
#define ROWS_PER_WAVE (ROWS_PER_BLOCK / NWAVES)  // 8
#define NBLK   (C_CLS * BPC)              // 1024
#define NF4    8                          // float4 per lane per row (64*8*4 = 2048)

__device__ __forceinline__ float wave_reduce_sum(float v) {
#pragma unroll
    for (int off = 32; off > 0; off >>= 1)
        v += __shfl_xor(v, off, 64);
    return v;
}

// PASS 0: first iteration. Computes squash scale per row, uniform weights (w=1).
// PASS 1: second iteration. b_new = scale*(z . c_prev)   (b was 0).
// PASS 2: third iteration.  b_new = b_old + scale*(z . c_prev).
// All passes accumulate unnormalized s = sum_k w_k * scale_k * z_k and sum_k w_k.
template <int PASS>
__global__ __launch_bounds__(256)
void route_pass(const float* __restrict__ z,
                float* __restrict__ scale,
                float* __restrict__ bvec,
                const float* __restrict__ c_prev,
                float* __restrict__ part_s,
                float* __restrict__ part_e)
{
    __shared__ float4 s_comb[NWAVES][D_DIM / 4];  // 32 KB
    __shared__ float  e_comb[NWAVES];

    const int blk  = blockIdx.x;
    const int cls  = blk / BPC;
    const int bic  = blk - cls * BPC;
    const int lane = threadIdx.x & 63;
    const int wid  = threadIdx.x >> 6;

    float4 cp[NF4];
    if (PASS != 0) {
        const float4* cp4 = (const float4*)(c_prev + (size_t)cls * D_DIM);
#pragma unroll
        for (int i = 0; i < NF4; ++i) cp[i] = cp4[lane + i * 64];
    }

    float4 acc[NF4];
#pragma unroll
    for (int i = 0; i < NF4; ++i) acc[i] = make_float4(0.f, 0.f, 0.f, 0.f);
    float esum = 0.f;

    const int k0 = bic * ROWS_PER_BLOCK + wid * ROWS_PER_WAVE;
    const float4* __restrict__ zbase =
        (const float4*)(z + ((size_t)cls * K_SHOTS + k0) * D_DIM);

    // double-buffered row streaming: load row r+1 while reducing row r
    float4 zcur[NF4];
#pragma unroll
    for (int i = 0; i < NF4; ++i) zcur[i] = zbase[lane + i * 64];

#pragma unroll
    for (int r = 0; r < ROWS_PER_WAVE; ++r) {
        float4 znext[NF4];
        if (r + 1 < ROWS_PER_WAVE) {
            const float4* zn = zbase + (size_t)(r + 1) * (D_DIM / 4);
#pragma unroll
            for (int i = 0; i < NF4; ++i) znext[i] = zn[lane + i * 64];
        }
        const int k = k0 + r;
        float w, sc;
        if (PASS == 0) {
            float n2 = 0.f;
#pragma unroll
            for (int i = 0; i < NF4; ++i) {
                n2 += zcur[i].x * zcur[i].x + zcur[i].y * zcur[i].y
                    + zcur[i].z * zcur[i].z + zcur[i].w * zcur[i].w;
            }
            n2 = wave_reduce_sum(n2);
            sc = sqrtf(n2) / (1.f + n2);          // squash scale for this row
            if (lane == 0) scale[cls * K_SHOTS + k] = sc;
            w = 1.f;                               // softmax(0) -> uniform (normalize later)
        } else {
            float dot = 0.f;
#pragma unroll
            for (int i = 0; i < NF4; ++i) {
                dot += zcur[i].x * cp[i].x + zcur[i].y * cp[i].y
                     + zcur[i].z * cp[i].z + zcur[i].w * cp[i].w;
            }
            dot = wave_reduce_sum(dot);
            sc = scale[cls * K_SHOTS + k];
            float bnew = sc * dot;                 // z_sq . c_prev
            if (PASS == 2) bnew += bvec[cls * K_SHOTS + k];
            if (lane == 0) bvec[cls * K_SHOTS + k] = bnew;
            w = expf(bnew);                        // unnormalized softmax weight
        }
        esum += w;
        const float wsc = w * sc;
#pragma unroll
        for (int i = 0; i < NF4; ++i) {
            acc[i].x += wsc * zcur[i].x;
            acc[i].y += wsc * zcur[i].y;
            acc[i].z += wsc * zcur[i].z;
            acc[i].w += wsc * zcur[i].w;
        }
        if (r + 1 < ROWS_PER_WAVE) {
#pragma unroll
            for (int i = 0; i < NF4; ++i) zcur[i] = znext[i];
        }
    }

    // deterministic 4-wave combine via LDS
#pragma unroll
    for (int i = 0; i < NF4; ++i) s_comb[wid][lane + i * 64] = acc[i];
    if (lane == 0) e_comb[wid] = esum;
    __syncthreads();

    float4* ps = (float4*)(part_s + (size_t)blk * D_DIM);
    const int t = threadIdx.x;
#pragma unroll
    for (int j = 0; j < 2; ++j) {
        const int f = t + j * 256;
        const float4 a = s_comb[0][f];
        const float4 b4 = s_comb[1][f];
        const float4 c4 = s_comb[2][f];
        const float4 d4 = s_comb[3][f];
        float4 s;
        s.x = (a.x + b4.x) + (c4.x + d4.x);
        s.y = (a.y + b4.y) + (c4.y + d4.y);
        s.z = (a.z + b4.z) + (c4.z + d4.z);
        s.w = (a.w + b4.w) + (c4.w + d4.w);
        ps[f] = s;
    }
    if (t == 0) part_e[blk] = (e_comb[0] + e_comb[1]) + (e_comb[2] + e_comb[3]);
}

// Sum the BPC partials per class (fixed order -> deterministic), normalize by
// sum(exp), squash, write c (or final output).
__global__ __launch_bounds__(256)
void reduce_squash(const float* __restrict__ part_s,
                   const float* __restrict__ part_e,
                   float* __restrict__ c_out)
{
    __shared__ float wred[NWAVES];
    const int cls  = blockIdx.x;
    const int t    = threadIdx.x;
    const int lane = t & 63;
    const int wid  = t >> 6;

    float esum = 0.f;
#pragma unroll
    for (int p = 0; p < BPC; ++p) esum += part_e[cls * BPC + p];
    const float inv = 1.f / esum;

    float4 m[2];
    float n2p = 0.f;
#pragma unroll
    for (int j = 0; j < 2; ++j) {
        const int f = t + j * 256;
        float4 s = make_float4(0.f, 0.f, 0.f, 0.f);
        for (int p = 0; p < BPC; ++p) {
            const float4 v =
                ((const float4*)(part_s + (size_t)(cls * BPC + p) * D_DIM))[f];
            s.x += v.x; s.y += v.y; s.z += v.z; s.w += v.w;
        }
        m[j].x = s.x * inv; m[j].y = s.y * inv;
        m[j].z = s.z * inv; m[j].w = s.w * inv;
        n2p += m[j].x * m[j].x + m[j].y * m[j].y
             + m[j].z * m[j].z + m[j].w * m[j].w;
    }
    float n2 = wave_reduce_sum(n2p);
    if (lane == 0) wred[wid] = n2;
    __syncthreads();
    n2 = (wred[0] + wred[1]) + (wred[2] + wred[3]);
    const float fac = sqrtf(n2) / (1.f + n2);

    float4* co = (float4*)(c_out + (size_t)cls * D_DIM);
#pragma unroll
    for (int j = 0; j < 2; ++j) {
        const int f = t + j * 256;
        float4 o;
        o.x = m[j].x * fac; o.y = m[j].y * fac;
        o.z = m[j].z * fac; o.w = m[j].w * fac;
        co[f] = o;
    }
}

extern "C" void kernel_launch(void* const* d_in, const int* in_sizes, int n_in,
                              void* d_out, int out_size, void* d_ws, size_t ws_size,
                              hipStream_t stream)
{
    const float* z = (const float*)d_in[0];
    float* out = (float*)d_out;
    float* ws  = (float*)d_ws;

    float* scale  = ws;                                   // C*K
    float* bvec   = scale + C_CLS * K_SHOTS;              // C*K
    float* c_buf  = bvec + C_CLS * K_SHOTS;               // C*D
    float* part_s = c_buf + (size_t)C_CLS * D_DIM;        // NBLK*D
    float* part_e = part_s + (size_t)NBLK * D_DIM;        // NBLK
    // total ws: ~8.8 MB

    route_pass<0><<<NBLK, 256, 0, stream>>>(z, scale, bvec, nullptr, part_s, part_e);
    reduce_squash<<<C_CLS, 256, 0, stream>>>(part_s, part_e, c_buf);

    route_pass<1><<<NBLK, 256, 0, stream>>>(z, scale, bvec, c_buf, part_s, part_e);
    reduce_squash<<<C_CLS, 256, 0, stream>>>(part_s, part_e, c_buf);

    route_pass<2><<<NBLK, 256, 0, stream>>>(z, scale, bvec, c_buf, part_s, part_e);
    reduce_squash<<<C_CLS, 256, 0, stream>>>(part_s, part_e, out);
}